// Round 10
// baseline (191.927 us; speedup 1.0000x reference)
//
#include <hip/hip_runtime.h>
#include <cstdint>

// MultiHeadAttention: B=2 S=2048 D=768 H=12 dk=64, fp32 in/out, bf16 MFMA inside.
//
//   convert_all : q,k,v,w_q,w_k,w_v,w_o fp32 -> bf16              (ws)
//   qkv         : R6 verbatim (BK=64 single-buffer; R7/R8 pipeline raced,
//                 R9 double-buffer neutral -> GEMMs are not drain-bound).
//   attn        : R10: wave = (par x T-HALF) instead of (par x q-half).
//                 Each wave owns 32 t-rows and computes BOTH 32-q sets,
//                 reusing every K/V fragment for 2 MFMAs -> LDS reads per
//                 block-phase 64 -> 32 (attn is LDS-pipe-bound, ~65% busy).
//                 Costs +48 VGPR (co x2, qf x2): LB(256,2) so no spill
//                 (R5's failure mode excluded; only s-tiles stay x2... they
//                 don't: 2 S-tiles as R3). 4-wave tree merge at end.
//   o           : R6 verbatim.

#define S_LEN 2048
#define NHEAD 12
#define DMODEL 768

typedef short s16x8 __attribute__((ext_vector_type(8)));
typedef float f32x4 __attribute__((ext_vector_type(4)));
typedef float f32x16 __attribute__((ext_vector_type(16)));

#define MFMA16(a, b, c) __builtin_amdgcn_mfma_f32_16x16x32_bf16((a), (b), (c), 0, 0, 0)
#define MFMA32(a, b, c) __builtin_amdgcn_mfma_f32_32x32x16_bf16((a), (b), (c), 0, 0, 0)

__device__ __forceinline__ void lds_dma16(void* lds, const void* g) {
  __builtin_amdgcn_global_load_lds(
      (const __attribute__((address_space(1))) unsigned int*)g,
      (__attribute__((address_space(3))) unsigned int*)lds, 16, 0, 0);
}

__device__ __forceinline__ unsigned int pk_bf16(float a, float b) {
  unsigned int ua = __float_as_uint(a), ub = __float_as_uint(b);
  ua = (ua + 0x7FFFu + ((ua >> 16) & 1u)) >> 16;   // RNE
  ub = (ub + 0x7FFFu + ((ub >> 16) & 1u)) >> 16;
  return ua | (ub << 16);
}
__device__ __forceinline__ short bf16r(float a) {
  unsigned int ua = __float_as_uint(a);
  return (short)((ua + 0x7FFFu + ((ua >> 16) & 1u)) >> 16);
}
// pack hi16(b)<<16 | hi16(a) in ONE v_perm_b32 (trunc; bias cancelled via l)
__device__ __forceinline__ unsigned int pk_trunc(float a, float b) {
  return __builtin_amdgcn_perm(__float_as_uint(b), __float_as_uint(a), 0x07060302u);
}
__device__ __forceinline__ float bf16_floor(float a) {
  return __uint_as_float(__float_as_uint(a) & 0xFFFF0000u);
}

// ---------------------------------------------------------------------------
// All fp32 -> bf16 conversions in ONE launch. (byte-identical to R6)
// ---------------------------------------------------------------------------
__global__ __launch_bounds__(256)
void convert_all(const float* __restrict__ q, const float* __restrict__ k,
                 const float* __restrict__ v,
                 const float* __restrict__ w0, const float* __restrict__ w1,
                 const float* __restrict__ w2, const float* __restrict__ w3,
                 short* __restrict__ qb, short* __restrict__ kb,
                 short* __restrict__ vb,
                 short* __restrict__ o0, short* __restrict__ o1,
                 short* __restrict__ o2, short* __restrict__ o3) {
  int b = blockIdx.x;
  const float* src;
  short* dst;
  if (b < 9216) {
    const int s = b / 3072;
    src = (s == 0) ? q : (s == 1) ? k : v;
    dst = (s == 0) ? qb : (s == 1) ? kb : vb;
    b -= s * 3072;
  } else {
    b -= 9216;
    const int s = b / 576;
    src = (s == 0) ? w0 : (s == 1) ? w1 : (s == 2) ? w2 : w3;
    dst = (s == 0) ? o0 : (s == 1) ? o1 : (s == 2) ? o2 : o3;
    b -= s * 576;
  }
  const long i = ((long)b * 256 + threadIdx.x) * 4;
  float4 f = *(const float4*)(src + i);
  uint2 u;
  u.x = pk_bf16(f.x, f.y);
  u.y = pk_bf16(f.z, f.w);
  *(uint2*)(dst + i) = u;
}

// ---------------------------------------------------------------------------
// Fused QKV projection. R6 verbatim: 576 blocks, XCD-swizzled, 128x128 tile,
// BK=64 single-buffered (12 iters), XOR-swizzled LDS.
// ---------------------------------------------------------------------------
__global__ __launch_bounds__(256)
void qkv_kernel(const short* __restrict__ qb, const short* __restrict__ kb,
                const short* __restrict__ vb,
                const short* __restrict__ wq, const short* __restrict__ wk,
                const short* __restrict__ wv,
                const float* __restrict__ bq, const float* __restrict__ bk,
                const float* __restrict__ bv,
                short* __restrict__ qh, short* __restrict__ kh,
                short* __restrict__ vt) {
  constexpr int K = 768;
  __shared__ short Abuf[128 * 64];   // [row][k], 128B rows, XOR-swizzled
  __shared__ short Bbuf[128 * 64];

  const int L   = blockIdx.x;        // 0..575
  const int xcd = L & 7;
  const int i   = L >> 3;            // 0..71
  const int nt  = i % 6;
  const int pl  = xcd * 12 + i / 6;  // 0..95 (m,z) pair
  const int z   = pl >> 5;           // 32 m-tiles per z
  const int mt  = pl & 31;
  const int m0  = mt * 128;          // token
  const int n0  = nt * 128;          // feature

  const short* A = (z == 0) ? qb : (z == 1) ? kb : vb;
  const short* B = (z == 0) ? wq : (z == 1) ? wk : wv;
  const float* bias = (z == 0) ? bq : (z == 1) ? bk : bv;

  const int tid  = threadIdx.x;
  const int lane = tid & 63;
  const int w    = tid >> 6;
  const int g    = lane >> 4;
  const int c    = lane & 15;
  const int wm   = (w & 1) * 64;
  const int wn   = (w >> 1) * 64;

  const int lr   = lane >> 3;
  const int dchk = ((lane & 7) ^ lr) * 8;
  const short* Ag = A + (long)(m0 + w * 32 + lr) * K + dchk;
  const short* Bg = B + (long)(n0 + w * 32 + lr) * K + dchk;
  short* Al = &Abuf[(w * 32) * 64];
  short* Bl = &Bbuf[(w * 32) * 64];

  f32x4 acc[4][4];
#pragma unroll
  for (int a = 0; a < 4; ++a)
#pragma unroll
    for (int b2 = 0; b2 < 4; ++b2) acc[a][b2] = (f32x4){0.f, 0.f, 0.f, 0.f};

  int aoff[4][2], boff[4][2];
#pragma unroll
  for (int mb = 0; mb < 4; ++mb)
#pragma unroll
    for (int kk = 0; kk < 2; ++kk) {
      const int Ra = wm + mb * 16 + c;
      const int Rb = wn + mb * 16 + c;
      aoff[mb][kk] = Ra * 64 + (((kk * 4 + g) ^ (Ra & 7)) * 8);
      boff[mb][kk] = Rb * 64 + (((kk * 4 + g) ^ (Rb & 7)) * 8);
    }

  for (int kt = 0; kt < K; kt += 64) {
#pragma unroll
    for (int ii = 0; ii < 4; ++ii) {
      lds_dma16(Al + ii * 8 * 64, Ag + (long)ii * 8 * K + kt);
      lds_dma16(Bl + ii * 8 * 64, Bg + (long)ii * 8 * K + kt);
    }
    __syncthreads();   // vmcnt(0) drain: DMA landed

#pragma unroll
    for (int kk = 0; kk < 2; ++kk) {
      s16x8 af[4], bf[4];
#pragma unroll
      for (int mb = 0; mb < 4; ++mb)
        af[mb] = *(const s16x8*)&Abuf[aoff[mb][kk]];
#pragma unroll
      for (int nb = 0; nb < 4; ++nb)
        bf[nb] = *(const s16x8*)&Bbuf[boff[nb][kk]];
#pragma unroll
      for (int mb = 0; mb < 4; ++mb)
#pragma unroll
        for (int nb = 0; nb < 4; ++nb)
          acc[mb][nb] = MFMA16(af[mb], bf[nb], acc[mb][nb]);
    }
    __syncthreads();   // safe to overwrite LDS
  }

  if (z < 2) {
    short* outp = z ? kh : qh;
    const float scale = z ? 1.0f : 0.18033688011112042f;  // log2e/8
#pragma unroll
    for (int mb = 0; mb < 4; ++mb) {
#pragma unroll
      for (int nb = 0; nb < 4; ++nb) {
        const int n = n0 + wn + nb * 16 + c;
        const float bvv = bias[n];
        const int hh = n >> 6, d = n & 63;
#pragma unroll
        for (int r = 0; r < 4; ++r) {
          const int m = m0 + wm + mb * 16 + g * 4 + r;
          const int b2 = m >> 11, s = m & 2047;
          const float val = (acc[mb][nb][r] + bvv) * scale;
          outp[(((long)(b2 * NHEAD + hh) * S_LEN + s) << 6) + d] = bf16r(val);
        }
      }
    }
  } else {  // V: transposed write Vt[b][h][d][t], 4 consecutive t per lane
#pragma unroll
    for (int mb = 0; mb < 4; ++mb) {
#pragma unroll
      for (int nb = 0; nb < 4; ++nb) {
        const int n = n0 + wn + nb * 16 + c;   // feature
        const float bvv = bias[n];
        const int hh = n >> 6, d = n & 63;
        const int m_base = m0 + wm + mb * 16 + g * 4;   // token base
        const int b2 = m_base >> 11, t = m_base & 2047;
        uint2 ov;
        ov.x = pk_bf16(acc[mb][nb][0] + bvv, acc[mb][nb][1] + bvv);
        ov.y = pk_bf16(acc[mb][nb][2] + bvv, acc[mb][nb][3] + bvv);
        *(uint2*)(vt + ((long)(b2 * NHEAD + hh) * 64 + d) * S_LEN + t) = ov;
      }
    }
  }
}

// ---------------------------------------------------------------------------
// Output projection. R6 verbatim: 384 blocks, 64x128 tile, BK=64.
// ---------------------------------------------------------------------------
__global__ __launch_bounds__(256)
void o_kernel(const short* __restrict__ ctx, const short* __restrict__ wo,
              const float* __restrict__ bo, float* __restrict__ out) {
  constexpr int K = 768;
  __shared__ short Abuf[64 * 64];
  __shared__ short Bbuf[128 * 64];

  const int L   = blockIdx.x;        // 0..383
  const int xcd = L & 7;
  const int i   = L >> 3;            // 0..47
  const int nt  = i % 6;
  const int mt  = xcd * 8 + i / 6;   // 0..63
  const int m0  = mt * 64;
  const int n0  = nt * 128;

  const int tid  = threadIdx.x;
  const int lane = tid & 63;
  const int w    = tid >> 6;
  const int g    = lane >> 4;
  const int c    = lane & 15;
  const int wm   = (w & 1) * 32;
  const int wn   = (w >> 1) * 64;

  const int lr   = lane >> 3;
  const int dchk = ((lane & 7) ^ lr) * 8;
  const short* Ag = ctx + (long)(m0 + w * 16 + lr) * K + dchk;
  const short* Bg = wo + (long)(n0 + w * 32 + lr) * K + dchk;
  short* Al = &Abuf[(w * 16) * 64];
  short* Bl = &Bbuf[(w * 32) * 64];

  f32x4 acc[2][4];
#pragma unroll
  for (int a = 0; a < 2; ++a)
#pragma unroll
    for (int b2 = 0; b2 < 4; ++b2) acc[a][b2] = (f32x4){0.f, 0.f, 0.f, 0.f};

  int aoff[2][2], boff[4][2];
#pragma unroll
  for (int kk = 0; kk < 2; ++kk) {
#pragma unroll
    for (int mb = 0; mb < 2; ++mb) {
      const int Ra = wm + mb * 16 + c;
      aoff[mb][kk] = Ra * 64 + (((kk * 4 + g) ^ (Ra & 7)) * 8);
    }
#pragma unroll
    for (int nb = 0; nb < 4; ++nb) {
      const int Rb = wn + nb * 16 + c;
      boff[nb][kk] = Rb * 64 + (((kk * 4 + g) ^ (Rb & 7)) * 8);
    }
  }

  for (int kt = 0; kt < K; kt += 64) {
#pragma unroll
    for (int ii = 0; ii < 2; ++ii)
      lds_dma16(Al + ii * 8 * 64, Ag + (long)ii * 8 * K + kt);
#pragma unroll
    for (int ii = 0; ii < 4; ++ii)
      lds_dma16(Bl + ii * 8 * 64, Bg + (long)ii * 8 * K + kt);
    __syncthreads();

#pragma unroll
    for (int kk = 0; kk < 2; ++kk) {
      s16x8 af[2], bf[4];
#pragma unroll
      for (int mb = 0; mb < 2; ++mb)
        af[mb] = *(const s16x8*)&Abuf[aoff[mb][kk]];
#pragma unroll
      for (int nb = 0; nb < 4; ++nb)
        bf[nb] = *(const s16x8*)&Bbuf[boff[nb][kk]];
#pragma unroll
      for (int mb = 0; mb < 2; ++mb)
#pragma unroll
        for (int nb = 0; nb < 4; ++nb)
          acc[mb][nb] = MFMA16(af[mb], bf[nb], acc[mb][nb]);
    }
    __syncthreads();
  }

#pragma unroll
  for (int mb = 0; mb < 2; ++mb) {
#pragma unroll
    for (int nb = 0; nb < 4; ++nb) {
      const int n = n0 + wn + nb * 16 + c;
      const float bvv = bo[n];
#pragma unroll
      for (int r = 0; r < 4; ++r) {
        const int m = m0 + wm + mb * 16 + g * 4 + r;
        out[(long)m * DMODEL + n] = acc[mb][nb][r] + bvv;
      }
    }
  }
}

// ---------------------------------------------------------------------------
// Flash attention, no-max softmax. R10: (par x t-half) wave partition.
// Wave w: par = w&1 (tile parity), th = w>>1 (t-rows [th*32, th*32+32)).
// Each wave computes BOTH q-sets (qA = q32, qB = 32+q32): every K fragment
// feeds 2 QK MFMAs, every V fragment 2 PV MFMAs -> LDS reads per block-phase
// 64 -> 32 (8 per wave: K 4, V 4). Staging = R3/R6 verbatim.
// Layouts (R3-verified): A/B frag m/n=lane&31, k=hi*8+j; C/D col=lane&31,
// row=(r&3)+8*(r>>2)+4*hi. K read row = th*32+q32; V rows q32 / 32+q32 with
// t-chunk (4*th + 2*sl + hi) ^ tw.
// End: 4-wave tree merge (par-merge A, then B; th-merge; wave 0 writes).
// ---------------------------------------------------------------------------
__global__ __launch_bounds__(256, 2)
void attn_kernel(const short* __restrict__ Qh, const short* __restrict__ Kh,
                 const short* __restrict__ Vt, short* __restrict__ Ctx) {
  __shared__ short kbuf[2][64 * 64];      // swizzled [t][d], per parity
  __shared__ short vbuf[2][64 * 64];      // swizzled [d][t], per parity

  const int tid  = threadIdx.x;
  const int lane = tid & 63;
  const int w    = tid >> 6;
  const int par  = w & 1;                 // tile parity
  const int th   = w >> 1;                // t-half within tile
  const int q32  = lane & 31;
  const int hi   = lane >> 5;
  const int bh   = blockIdx.y;            // 0..23
  const int qs0  = blockIdx.x * 64;
  const long base = (long)bh * S_LEN * 64;
  const short* Qb = Qh + base;
  const short* Kb = Kh + base;
  const short* Vb = Vt + base;

  // Q fragments (B operand), BOTH qsets: n=q, k=d = db*16 + hi*8 + j
  s16x8 qfA[4], qfB[4];
  {
    const long qrA = (long)(qs0 + q32) * 64;
    const long qrB = (long)(qs0 + 32 + q32) * 64;
#pragma unroll
    for (int db = 0; db < 4; ++db) {
      qfA[db] = *(const s16x8*)(Qb + qrA + db * 16 + hi * 8);
      qfB[db] = *(const s16x8*)(Qb + qrB + db * 16 + hi * 8);
    }
  }

  f32x16 coA0, coA1, coB0, coB1;
#pragma unroll
  for (int i = 0; i < 16; ++i) {
    coA0[i] = 0.f; coA1[i] = 0.f; coB0[i] = 0.f; coB1[i] = 0.f;
  }
  float lA = 0.f, lB = 0.f;

  // ---- staging identities (R3 verbatim) ----
  const int srow = tid >> 2;           // 0..63 (t-row for K, d-row for V)
  const int sq   = tid & 3;
  const int sw   = srow & 7;
  const int sg0  = ((2 * sq)     ^ sw) * 8;
  const int sg1  = ((2 * sq + 1) ^ sw) * 8;
  const short* kg = Kb + (long)srow * 64 + sq * 16;
  const short* vg = Vb + (long)srow * S_LEN + sq * 16;

  uint4 rkE0, rkE1, rvE0, rvE1, rkO0, rkO1, rvO0, rvO1;
  auto fetch_pair = [&](long tE, long tO) {
    rkE0 = *(const uint4*)(kg + tE * 64);
    rkE1 = *(const uint4*)(kg + tE * 64 + 8);
    rvE0 = *(const uint4*)(vg + tE);
    rvE1 = *(const uint4*)(vg + tE + 8);
    rkO0 = *(const uint4*)(kg + tO * 64);
    rkO1 = *(const uint4*)(kg + tO * 64 + 8);
    rvO0 = *(const uint4*)(vg + tO);
    rvO1 = *(const uint4*)(vg + tO + 8);
  };
  auto store_pair = [&]() {
    *(uint4*)&kbuf[0][srow * 64 + sg0] = rkE0;
    *(uint4*)&kbuf[0][srow * 64 + sg1] = rkE1;
    *(uint4*)&vbuf[0][srow * 64 + sg0] = rvE0;
    *(uint4*)&vbuf[0][srow * 64 + sg1] = rvE1;
    *(uint4*)&kbuf[1][srow * 64 + sg0] = rkO0;
    *(uint4*)&kbuf[1][srow * 64 + sg1] = rkO1;
    *(uint4*)&vbuf[1][srow * 64 + sg0] = rvO0;
    *(uint4*)&vbuf[1][srow * 64 + sg1] = rvO1;
  };

  // ---- read-side offsets ----
  const int tw = lane & 7;
  int c4[4];
#pragma unroll
  for (int i = 0; i < 4; ++i) c4[i] = ((2 * i + hi) ^ tw) * 8;
  int ct[2];
#pragma unroll
  for (int sl = 0; sl < 2; ++sl) ct[sl] = ((4 * th + 2 * sl + hi) ^ tw) * 8;
  const int row0 = q32 * 64;
  const int row1 = (32 + q32) * 64;
  const int rowK = th ? row1 : row0;   // K row = (th*32 + q32)*64
  const short* kb2 = kbuf[par];
  const short* vb2 = vbuf[par];

  // P->B-frag builder (R3-verified): two permlane32_swaps.
  auto mkfrag = [&](unsigned a, unsigned b, unsigned c, unsigned d) -> s16x8 {
    asm("v_permlane32_swap_b32 %0, %1" : "+v"(a), "+v"(c));
    asm("v_permlane32_swap_b32 %0, %1" : "+v"(b), "+v"(d));
    uint4 u;
    u.x = a; u.y = b; u.z = c; u.w = d;
    return __builtin_bit_cast(s16x8, u);
  };

  auto step = [&]() {
    // K frags for this wave's 32 t-rows (shared by both qsets)
    s16x8 kf[4];
#pragma unroll
    for (int db = 0; db < 4; ++db)
      kf[db] = *(const s16x8*)&kb2[rowK + c4[db]];
    // QK^T for qset A, then qset B (kf reused)
    f32x16 sA, sB;
#pragma unroll
    for (int i = 0; i < 16; ++i) { sA[i] = 0.f; sB[i] = 0.f; }
    __builtin_amdgcn_s_setprio(1);
#pragma unroll
    for (int db = 0; db < 4; ++db) sA = MFMA32(kf[db], qfA[db], sA);
#pragma unroll
    for (int db = 0; db < 4; ++db) sB = MFMA32(kf[db], qfB[db], sB);
    __builtin_amdgcn_s_setprio(0);
    // softmax (no-max): exp2, l-accumulate, pack
    unsigned pkA[8], pkB[8];
    float la = 0.f, lb = 0.f;
#pragma unroll
    for (int i = 0; i < 8; ++i) {
      float a0 = __builtin_amdgcn_exp2f(sA[2 * i]);
      float a1 = __builtin_amdgcn_exp2f(sA[2 * i + 1]);
      la += bf16_floor(a0) + bf16_floor(a1);
      pkA[i] = pk_trunc(a0, a1);
      float b0 = __builtin_amdgcn_exp2f(sB[2 * i]);
      float b1 = __builtin_amdgcn_exp2f(sB[2 * i + 1]);
      lb += bf16_floor(b0) + bf16_floor(b1);
      pkB[i] = pk_trunc(b0, b1);
    }
    lA += la;
    lB += lb;
    // B-frags: slice0 = t-local 0..15 (regs 0..7), slice1 = 16..31
    s16x8 pfA[2], pfB[2];
    pfA[0] = mkfrag(pkA[0], pkA[1], pkA[2], pkA[3]);
    pfA[1] = mkfrag(pkA[4], pkA[5], pkA[6], pkA[7]);
    pfB[0] = mkfrag(pkB[0], pkB[1], pkB[2], pkB[3]);
    pfB[1] = mkfrag(pkB[4], pkB[5], pkB[6], pkB[7]);
    // PV: co[d][q] += V[d][t-slice] * P[t-slice][q] (V frags reused x2)
    __builtin_amdgcn_s_setprio(1);
#pragma unroll
    for (int sl = 0; sl < 2; ++sl) {
      const s16x8 v0 = *(const s16x8*)&vb2[row0 + ct[sl]];
      const s16x8 v1 = *(const s16x8*)&vb2[row1 + ct[sl]];
      coA0 = MFMA32(v0, pfA[sl], coA0);
      coA1 = MFMA32(v1, pfA[sl], coA1);
      coB0 = MFMA32(v0, pfB[sl], coB0);
      coB1 = MFMA32(v1, pfB[sl], coB1);
    }
    __builtin_amdgcn_s_setprio(0);
  };

  constexpr int NT = S_LEN / 64;   // 32 tiles, 16 phases
  fetch_pair(0, 64);
  store_pair();
  for (int ph = 0; ph < NT / 2; ++ph) {
    __syncthreads();                               // both buffers ready
    const long tE = (2 * ph + 2 < NT) ? (long)(2 * ph + 2) * 64 : 0;
    const long tO = (2 * ph + 3 < NT) ? (long)(2 * ph + 3) * 64 : 0;
    fetch_pair(tE, tO);                            // overlap with step
    step();                                        // wave's (par, th) slice
    __syncthreads();                               // all done reading
    store_pair();                                  // refill both buffers
  }

  // combine hi-halves (same q, complementary t-rows within the wave's slice)
  float rsA = lA + __shfl_xor(lA, 32);
  float rsB = lB + __shfl_xor(lB, 32);

  // ---- 4-wave tree merge via LDS (stride 36 floats = 144B) ----
  float* RK = (float*)kbuf;
  float* RV = (float*)vbuf;
  auto dump = [&](float* R, const f32x16& x0, const f32x16& x1, float rs) {
    float* mp = R + lane * 36;
#pragma unroll
    for (int i = 0; i < 4; ++i) {
      *(float4*)(mp + 4 * i)      = make_float4(x0[4*i], x0[4*i+1], x0[4*i+2], x0[4*i+3]);
      *(float4*)(mp + 16 + 4 * i) = make_float4(x1[4*i], x1[4*i+1], x1[4*i+2], x1[4*i+3]);
    }
    mp[32] = rs;
  };
  auto addin = [&](const float* R, f32x16& x0, f32x16& x1, float& rs) {
    const float* mp = R + lane * 36;
#pragma unroll
    for (int i = 0; i < 4; ++i) {
      float4 a = *(const float4*)(mp + 4 * i);
      float4 b = *(const float4*)(mp + 16 + 4 * i);
      x0[4*i] += a.x; x0[4*i+1] += a.y; x0[4*i+2] += a.z; x0[4*i+3] += a.w;
      x1[4*i] += b.x; x1[4*i+1] += b.y; x1[4*i+2] += b.z; x1[4*i+3] += b.w;
    }
    rs += mp[32];
  };

  __syncthreads();   // last store_pair done; safe to reuse staging LDS
  // stage 1: par-merge (w1 -> w0 via RK, w3 -> w2 via RV), qset A then B
  if (par == 1) dump(th ? RV : RK, coA0, coA1, rsA);
  __syncthreads();
  if (par == 0) addin(th ? RV : RK, coA0, coA1, rsA);
  __syncthreads();
  if (par == 1) dump(th ? RV : RK, coB0, coB1, rsB);
  __syncthreads();
  if (par == 0) addin(th ? RV : RK, coB0, coB1, rsB);
  __syncthreads();
  // stage 2: th-merge (w2 -> w0): A via RK, B via RV
  if (par == 0 && th == 1) {
    dump(RK, coA0, coA1, rsA);
    dump(RV, coB0, coB1, rsB);
  }
  __syncthreads();
  if (w == 0) {
    addin(RK, coA0, coA1, rsA);
    addin(RV, coB0, coB1, rsB);
    const float invA = 1.f / rsA;
    const float invB = 1.f / rsB;

    const int hh = bh % NHEAD;
    const long tokA = (long)(bh / NHEAD) * S_LEN + qs0 + q32;
    short* opA = Ctx + tokA * DMODEL + hh * 64;
    short* opB = opA + (long)32 * DMODEL;   // token qs0+32+q32
    // reg r -> d = (r&3) + 8*(r>>2) + 4*hi (+32 for d-tile1)
#pragma unroll
    for (int rq = 0; rq < 4; ++rq) {
      const int d0 = 8 * rq + 4 * hi;
      uint2 ov;
      ov.x = pk_bf16(coA0[4*rq] * invA, coA0[4*rq+1] * invA);
      ov.y = pk_bf16(coA0[4*rq+2] * invA, coA0[4*rq+3] * invA);
      *(uint2*)(opA + d0) = ov;
      ov.x = pk_bf16(coA1[4*rq] * invA, coA1[4*rq+1] * invA);
      ov.y = pk_bf16(coA1[4*rq+2] * invA, coA1[4*rq+3] * invA);
      *(uint2*)(opA + 32 + d0) = ov;
      ov.x = pk_bf16(coB0[4*rq] * invB, coB0[4*rq+1] * invB);
      ov.y = pk_bf16(coB0[4*rq+2] * invB, coB0[4*rq+3] * invB);
      *(uint2*)(opB + d0) = ov;
      ov.x = pk_bf16(coB1[4*rq] * invB, coB1[4*rq+1] * invB);
      ov.y = pk_bf16(coB1[4*rq+2] * invB, coB1[4*rq+3] * invB);
      *(uint2*)(opB + 32 + d0) = ov;
    }
  }
}

// ---------------------------------------------------------------------------
extern "C" void kernel_launch(void* const* d_in, const int* in_sizes, int n_in,
                              void* d_out, int out_size, void* d_ws, size_t ws_size,
                              hipStream_t stream) {
  const float* q   = (const float*)d_in[0];
  const float* k   = (const float*)d_in[1];
  const float* v   = (const float*)d_in[2];
  const float* w_q = (const float*)d_in[3];
  const float* b_q = (const float*)d_in[4];
  const float* w_k = (const float*)d_in[5];
  const float* b_k = (const float*)d_in[6];
  const float* w_v = (const float*)d_in[7];
  const float* b_v = (const float*)d_in[8];
  const float* w_o = (const float*)d_in[9];
  const float* b_o = (const float*)d_in[10];
  float* out = (float*)d_out;

  const long NELEM = (long)2 * NHEAD * S_LEN * 64;  // 3,145,728
  const long WELEM = (long)DMODEL * DMODEL;         // 589,824
  short* qh  = (short*)d_ws;
  short* kh  = qh + NELEM;
  short* vt  = kh + NELEM;
  short* wqb = vt + NELEM;
  short* wkb = wqb + WELEM;
  short* wvb = wkb + WELEM;
  short* wob = wvb + WELEM;
  short* qb  = wob + WELEM;
  short* kb  = qb + NELEM;
  short* vb  = kb + NELEM;
  short* ctx = qb;   // alias: qb dead after qkv_kernel; attn writes ctx after

  dim3 blk(256);
  convert_all<<<dim3(11520), blk, 0, stream>>>(q, k, v, w_q, w_k, w_v, w_o,
                                               qb, kb, vb, wqb, wkb, wvb, wob);
  qkv_kernel<<<dim3(576), blk, 0, stream>>>(qb, kb, vb, wqb, wkb, wvb,
                                            b_q, b_k, b_v, qh, kh, vt);
  attn_kernel<<<dim3(32, 24), blk, 0, stream>>>(qh, kh, vt, ctx);
  o_kernel<<<dim3(384), blk, 0, stream>>>(ctx, wob, b_o, out);
}

// Round 11
// 187.626 us; speedup vs baseline: 1.0229x; 1.0229x over previous
//
#include <hip/hip_runtime.h>
#include <cstdint>

// MultiHeadAttention: B=2 S=2048 D=768 H=12 dk=64, fp32 in/out, bf16 MFMA inside.
//
// FINAL (R11 = R6 verbatim, the best verified config: 188.0us).
//   convert_all : q,k,v,w_q,w_k,w_v,w_o fp32 -> bf16              (ws)
//   qkv         : BK=64 single-buffer DMA GEMM, XOR-swizzled LDS.
//                 (R7/R8 counted-vmcnt pipeline raced; R9 double-buffer
//                 neutral -> GEMMs are not drain-bound at this size.)
//   attn        : flash attention, 32x32x16 MFMA, in-reg P (permlane32),
//                 (par x q-half) partition, 43.0us verified 3x.
//                 (R4 direct-V: latency-bound; R5 2x-reuse: VGPR spill;
//                 R10 t-half partition: conflicts halved but occupancy
//                 23->15% net -7us -> residency beats LDS-op count.)
//   o           : BK=64 single-buffer, 64x128 tile.

#define S_LEN 2048
#define NHEAD 12
#define DMODEL 768

typedef short s16x8 __attribute__((ext_vector_type(8)));
typedef float f32x4 __attribute__((ext_vector_type(4)));
typedef float f32x16 __attribute__((ext_vector_type(16)));

#define MFMA16(a, b, c) __builtin_amdgcn_mfma_f32_16x16x32_bf16((a), (b), (c), 0, 0, 0)
#define MFMA32(a, b, c) __builtin_amdgcn_mfma_f32_32x32x16_bf16((a), (b), (c), 0, 0, 0)

__device__ __forceinline__ void lds_dma16(void* lds, const void* g) {
  __builtin_amdgcn_global_load_lds(
      (const __attribute__((address_space(1))) unsigned int*)g,
      (__attribute__((address_space(3))) unsigned int*)lds, 16, 0, 0);
}

__device__ __forceinline__ unsigned int pk_bf16(float a, float b) {
  unsigned int ua = __float_as_uint(a), ub = __float_as_uint(b);
  ua = (ua + 0x7FFFu + ((ua >> 16) & 1u)) >> 16;   // RNE
  ub = (ub + 0x7FFFu + ((ub >> 16) & 1u)) >> 16;
  return ua | (ub << 16);
}
__device__ __forceinline__ short bf16r(float a) {
  unsigned int ua = __float_as_uint(a);
  return (short)((ua + 0x7FFFu + ((ua >> 16) & 1u)) >> 16);
}
// pack hi16(b)<<16 | hi16(a) in ONE v_perm_b32 (trunc; bias cancelled via l)
__device__ __forceinline__ unsigned int pk_trunc(float a, float b) {
  return __builtin_amdgcn_perm(__float_as_uint(b), __float_as_uint(a), 0x07060302u);
}
__device__ __forceinline__ float bf16_floor(float a) {
  return __uint_as_float(__float_as_uint(a) & 0xFFFF0000u);
}

// ---------------------------------------------------------------------------
// All fp32 -> bf16 conversions in ONE launch. 11520 blocks x 256 thr x
// float4/thr: blocks [0,9216) = q,k,v (3072 each); [9216,11520) = 4 weights
// (576 each).
// ---------------------------------------------------------------------------
__global__ __launch_bounds__(256)
void convert_all(const float* __restrict__ q, const float* __restrict__ k,
                 const float* __restrict__ v,
                 const float* __restrict__ w0, const float* __restrict__ w1,
                 const float* __restrict__ w2, const float* __restrict__ w3,
                 short* __restrict__ qb, short* __restrict__ kb,
                 short* __restrict__ vb,
                 short* __restrict__ o0, short* __restrict__ o1,
                 short* __restrict__ o2, short* __restrict__ o3) {
  int b = blockIdx.x;
  const float* src;
  short* dst;
  if (b < 9216) {
    const int s = b / 3072;
    src = (s == 0) ? q : (s == 1) ? k : v;
    dst = (s == 0) ? qb : (s == 1) ? kb : vb;
    b -= s * 3072;
  } else {
    b -= 9216;
    const int s = b / 576;
    src = (s == 0) ? w0 : (s == 1) ? w1 : (s == 2) ? w2 : w3;
    dst = (s == 0) ? o0 : (s == 1) ? o1 : (s == 2) ? o2 : o3;
    b -= s * 576;
  }
  const long i = ((long)b * 256 + threadIdx.x) * 4;
  float4 f = *(const float4*)(src + i);
  uint2 u;
  u.x = pk_bf16(f.x, f.y);
  u.y = pk_bf16(f.z, f.w);
  *(uint2*)(dst + i) = u;
}

// ---------------------------------------------------------------------------
// Fused QKV projection. 576 blocks, XCD-swizzled. Tile 128x128, BK=64
// (12 iters). LDS rows of 64 shorts (128B). Swizzle: LDS[row][pos] holds
// global chunk pos^(row&7); DMA keeps dest linear, source chunk =
// (lane&7)^(lane>>3). Reads: chunk p=kk*4+g at row R -> position p^(R&7).
// ---------------------------------------------------------------------------
__global__ __launch_bounds__(256)
void qkv_kernel(const short* __restrict__ qb, const short* __restrict__ kb,
                const short* __restrict__ vb,
                const short* __restrict__ wq, const short* __restrict__ wk,
                const short* __restrict__ wv,
                const float* __restrict__ bq, const float* __restrict__ bk,
                const float* __restrict__ bv,
                short* __restrict__ qh, short* __restrict__ kh,
                short* __restrict__ vt) {
  constexpr int K = 768;
  __shared__ short Abuf[128 * 64];   // [row][k], 128B rows, XOR-swizzled
  __shared__ short Bbuf[128 * 64];

  const int L   = blockIdx.x;        // 0..575
  const int xcd = L & 7;
  const int i   = L >> 3;            // 0..71
  const int nt  = i % 6;
  const int pl  = xcd * 12 + i / 6;  // 0..95 (m,z) pair
  const int z   = pl >> 5;           // 32 m-tiles per z
  const int mt  = pl & 31;
  const int m0  = mt * 128;          // token
  const int n0  = nt * 128;          // feature

  const short* A = (z == 0) ? qb : (z == 1) ? kb : vb;
  const short* B = (z == 0) ? wq : (z == 1) ? wk : wv;
  const float* bias = (z == 0) ? bq : (z == 1) ? bk : bv;

  const int tid  = threadIdx.x;
  const int lane = tid & 63;
  const int w    = tid >> 6;
  const int g    = lane >> 4;
  const int c    = lane & 15;
  const int wm   = (w & 1) * 64;
  const int wn   = (w >> 1) * 64;

  // DMA: wave w covers rows [w*32, w*32+32) per matrix, 4 insts x 8 rows.
  // lane -> local row lane>>3, pos lane&7; source chunk (lane&7)^(lane>>3).
  const int lr   = lane >> 3;
  const int dchk = ((lane & 7) ^ lr) * 8;
  const short* Ag = A + (long)(m0 + w * 32 + lr) * K + dchk;
  const short* Bg = B + (long)(n0 + w * 32 + lr) * K + dchk;
  short* Al = &Abuf[(w * 32) * 64];
  short* Bl = &Bbuf[(w * 32) * 64];

  f32x4 acc[4][4];
#pragma unroll
  for (int a = 0; a < 4; ++a)
#pragma unroll
    for (int b2 = 0; b2 < 4; ++b2) acc[a][b2] = (f32x4){0.f, 0.f, 0.f, 0.f};

  // read-side swizzled offsets (row R, chunk p -> R*64 + (p^(R&7))*8)
  int aoff[4][2], boff[4][2];
#pragma unroll
  for (int mb = 0; mb < 4; ++mb)
#pragma unroll
    for (int kk = 0; kk < 2; ++kk) {
      const int Ra = wm + mb * 16 + c;
      const int Rb = wn + mb * 16 + c;
      aoff[mb][kk] = Ra * 64 + (((kk * 4 + g) ^ (Ra & 7)) * 8);
      boff[mb][kk] = Rb * 64 + (((kk * 4 + g) ^ (Rb & 7)) * 8);
    }

  for (int kt = 0; kt < K; kt += 64) {
#pragma unroll
    for (int ii = 0; ii < 4; ++ii) {
      lds_dma16(Al + ii * 8 * 64, Ag + (long)ii * 8 * K + kt);
      lds_dma16(Bl + ii * 8 * 64, Bg + (long)ii * 8 * K + kt);
    }
    __syncthreads();   // vmcnt(0) drain: DMA landed

#pragma unroll
    for (int kk = 0; kk < 2; ++kk) {
      s16x8 af[4], bf[4];
#pragma unroll
      for (int mb = 0; mb < 4; ++mb)
        af[mb] = *(const s16x8*)&Abuf[aoff[mb][kk]];
#pragma unroll
      for (int nb = 0; nb < 4; ++nb)
        bf[nb] = *(const s16x8*)&Bbuf[boff[nb][kk]];
#pragma unroll
      for (int mb = 0; mb < 4; ++mb)
#pragma unroll
        for (int nb = 0; nb < 4; ++nb)
          acc[mb][nb] = MFMA16(af[mb], bf[nb], acc[mb][nb]);
    }
    __syncthreads();   // safe to overwrite LDS
  }

  if (z < 2) {
    short* outp = z ? kh : qh;
    const float scale = z ? 1.0f : 0.18033688011112042f;  // log2e/8
#pragma unroll
    for (int mb = 0; mb < 4; ++mb) {
#pragma unroll
      for (int nb = 0; nb < 4; ++nb) {
        const int n = n0 + wn + nb * 16 + c;
        const float bvv = bias[n];
        const int hh = n >> 6, d = n & 63;
#pragma unroll
        for (int r = 0; r < 4; ++r) {
          const int m = m0 + wm + mb * 16 + g * 4 + r;
          const int b2 = m >> 11, s = m & 2047;
          const float val = (acc[mb][nb][r] + bvv) * scale;
          outp[(((long)(b2 * NHEAD + hh) * S_LEN + s) << 6) + d] = bf16r(val);
        }
      }
    }
  } else {  // V: transposed write Vt[b][h][d][t], 4 consecutive t per lane
#pragma unroll
    for (int mb = 0; mb < 4; ++mb) {
#pragma unroll
      for (int nb = 0; nb < 4; ++nb) {
        const int n = n0 + wn + nb * 16 + c;   // feature
        const float bvv = bias[n];
        const int hh = n >> 6, d = n & 63;
        const int m_base = m0 + wm + mb * 16 + g * 4;   // token base
        const int b2 = m_base >> 11, t = m_base & 2047;
        uint2 ov;
        ov.x = pk_bf16(acc[mb][nb][0] + bvv, acc[mb][nb][1] + bvv);
        ov.y = pk_bf16(acc[mb][nb][2] + bvv, acc[mb][nb][3] + bvv);
        *(uint2*)(vt + ((long)(b2 * NHEAD + hh) * 64 + d) * S_LEN + t) = ov;
      }
    }
  }
}

// ---------------------------------------------------------------------------
// Output projection. 384 blocks, XCD-swizzled. 64x128 tile, BK=64
// (12 iters, same swizzle scheme as qkv). Wave tile 32x64, acc[2][4].
// ---------------------------------------------------------------------------
__global__ __launch_bounds__(256)
void o_kernel(const short* __restrict__ ctx, const short* __restrict__ wo,
              const float* __restrict__ bo, float* __restrict__ out) {
  constexpr int K = 768;
  __shared__ short Abuf[64 * 64];
  __shared__ short Bbuf[128 * 64];

  const int L   = blockIdx.x;        // 0..383
  const int xcd = L & 7;
  const int i   = L >> 3;            // 0..47
  const int nt  = i % 6;
  const int mt  = xcd * 8 + i / 6;   // 0..63
  const int m0  = mt * 64;
  const int n0  = nt * 128;

  const int tid  = threadIdx.x;
  const int lane = tid & 63;
  const int w    = tid >> 6;
  const int g    = lane >> 4;
  const int c    = lane & 15;
  const int wm   = (w & 1) * 32;
  const int wn   = (w >> 1) * 64;

  // DMA: A wave rows [w*16,+16) = 2 insts; B rows [w*32,+32) = 4 insts.
  const int lr   = lane >> 3;
  const int dchk = ((lane & 7) ^ lr) * 8;
  const short* Ag = ctx + (long)(m0 + w * 16 + lr) * K + dchk;
  const short* Bg = wo + (long)(n0 + w * 32 + lr) * K + dchk;
  short* Al = &Abuf[(w * 16) * 64];
  short* Bl = &Bbuf[(w * 32) * 64];

  f32x4 acc[2][4];
#pragma unroll
  for (int a = 0; a < 2; ++a)
#pragma unroll
    for (int b2 = 0; b2 < 4; ++b2) acc[a][b2] = (f32x4){0.f, 0.f, 0.f, 0.f};

  int aoff[2][2], boff[4][2];
#pragma unroll
  for (int kk = 0; kk < 2; ++kk) {
#pragma unroll
    for (int mb = 0; mb < 2; ++mb) {
      const int Ra = wm + mb * 16 + c;
      aoff[mb][kk] = Ra * 64 + (((kk * 4 + g) ^ (Ra & 7)) * 8);
    }
#pragma unroll
    for (int nb = 0; nb < 4; ++nb) {
      const int Rb = wn + nb * 16 + c;
      boff[nb][kk] = Rb * 64 + (((kk * 4 + g) ^ (Rb & 7)) * 8);
    }
  }

  for (int kt = 0; kt < K; kt += 64) {
#pragma unroll
    for (int ii = 0; ii < 2; ++ii)
      lds_dma16(Al + ii * 8 * 64, Ag + (long)ii * 8 * K + kt);
#pragma unroll
    for (int ii = 0; ii < 4; ++ii)
      lds_dma16(Bl + ii * 8 * 64, Bg + (long)ii * 8 * K + kt);
    __syncthreads();

#pragma unroll
    for (int kk = 0; kk < 2; ++kk) {
      s16x8 af[2], bf[4];
#pragma unroll
      for (int mb = 0; mb < 2; ++mb)
        af[mb] = *(const s16x8*)&Abuf[aoff[mb][kk]];
#pragma unroll
      for (int nb = 0; nb < 4; ++nb)
        bf[nb] = *(const s16x8*)&Bbuf[boff[nb][kk]];
#pragma unroll
      for (int mb = 0; mb < 2; ++mb)
#pragma unroll
        for (int nb = 0; nb < 4; ++nb)
          acc[mb][nb] = MFMA16(af[mb], bf[nb], acc[mb][nb]);
    }
    __syncthreads();
  }

#pragma unroll
  for (int mb = 0; mb < 2; ++mb) {
#pragma unroll
    for (int nb = 0; nb < 4; ++nb) {
      const int n = n0 + wn + nb * 16 + c;
      const float bvv = bo[n];
#pragma unroll
      for (int r = 0; r < 4; ++r) {
        const int m = m0 + wm + mb * 16 + g * 4 + r;
        out[(long)m * DMODEL + n] = acc[mb][nb][r] + bvv;
      }
    }
  }
}

// ---------------------------------------------------------------------------
// Flash attention, no-max softmax. Verified 43.0us (R3/R6/R9 reproduced).
// 4 waves/block, QBLK=64: wave = (rh = w>>1) x (par = w&1). 32x32x16 MFMA,
// in-register P via pk_trunc + v_permlane32_swap_b32, reg-staged XOR K/V.
// ---------------------------------------------------------------------------
__global__ __launch_bounds__(256, 3)
void attn_kernel(const short* __restrict__ Qh, const short* __restrict__ Kh,
                 const short* __restrict__ Vt, short* __restrict__ Ctx) {
  __shared__ short kbuf[2][64 * 64];      // swizzled [t][d], per parity
  __shared__ short vbuf[2][64 * 64];      // swizzled [d][t], per parity

  const int tid  = threadIdx.x;
  const int lane = tid & 63;
  const int w    = tid >> 6;
  const int par  = w & 1;                 // tile parity
  const int rh   = w >> 1;                // q-row half
  const int q32  = lane & 31;
  const int hi   = lane >> 5;
  const int bh   = blockIdx.y;            // 0..23
  const int qs0  = blockIdx.x * 64;
  const long base = (long)bh * S_LEN * 64;
  const short* Qb = Qh + base;
  const short* Kb = Kh + base;
  const short* Vb = Vt + base;

  // Q fragments (B operand): n=q32, k=d = db*16 + hi*8 + j
  const long qrow = (long)(qs0 + rh * 32 + q32) * 64;
  s16x8 qf[4];
#pragma unroll
  for (int db = 0; db < 4; ++db)
    qf[db] = *(const s16x8*)(Qb + qrow + db * 16 + hi * 8);

  f32x16 co0, co1;
#pragma unroll
  for (int i = 0; i < 16; ++i) { co0[i] = 0.f; co1[i] = 0.f; }
  float l_lane = 0.f;

  // ---- staging identities ----
  const int srow = tid >> 2;           // 0..63 (t-row for K, d-row for V)
  const int sq   = tid & 3;
  const int sw   = srow & 7;
  const int sg0  = ((2 * sq)     ^ sw) * 8;
  const int sg1  = ((2 * sq + 1) ^ sw) * 8;
  const short* kg = Kb + (long)srow * 64 + sq * 16;
  const short* vg = Vb + (long)srow * S_LEN + sq * 16;

  uint4 rkE0, rkE1, rvE0, rvE1, rkO0, rkO1, rvO0, rvO1;
  auto fetch_pair = [&](long tE, long tO) {
    rkE0 = *(const uint4*)(kg + tE * 64);
    rkE1 = *(const uint4*)(kg + tE * 64 + 8);
    rvE0 = *(const uint4*)(vg + tE);
    rvE1 = *(const uint4*)(vg + tE + 8);
    rkO0 = *(const uint4*)(kg + tO * 64);
    rkO1 = *(const uint4*)(kg + tO * 64 + 8);
    rvO0 = *(const uint4*)(vg + tO);
    rvO1 = *(const uint4*)(vg + tO + 8);
  };
  auto store_pair = [&]() {
    *(uint4*)&kbuf[0][srow * 64 + sg0] = rkE0;
    *(uint4*)&kbuf[0][srow * 64 + sg1] = rkE1;
    *(uint4*)&vbuf[0][srow * 64 + sg0] = rvE0;
    *(uint4*)&vbuf[0][srow * 64 + sg1] = rvE1;
    *(uint4*)&kbuf[1][srow * 64 + sg0] = rkO0;
    *(uint4*)&kbuf[1][srow * 64 + sg1] = rkO1;
    *(uint4*)&vbuf[1][srow * 64 + sg0] = rvO0;
    *(uint4*)&vbuf[1][srow * 64 + sg1] = rvO1;
  };

  // ---- read-side precomputed offsets ----
  const int tw = lane & 7;
  int c4[4];
#pragma unroll
  for (int i = 0; i < 4; ++i) c4[i] = ((2 * i + hi) ^ tw) * 8;
  const int row0 = q32 * 64;          // Mtile0 (shorts)
  const int row1 = (32 + q32) * 64;   // Mtile1
  const short* kb2 = kbuf[par];
  const short* vb2 = vbuf[par];

  // P->B-frag builder: words [a', b', c', d'] after two permlane32_swaps.
  auto mkfrag = [&](unsigned a, unsigned b, unsigned c, unsigned d) -> s16x8 {
    asm("v_permlane32_swap_b32 %0, %1" : "+v"(a), "+v"(c));
    asm("v_permlane32_swap_b32 %0, %1" : "+v"(b), "+v"(d));
    uint4 u;
    u.x = a; u.y = b; u.z = c; u.w = d;
    return __builtin_bit_cast(s16x8, u);
  };

  auto step = [&]() {
    // QK^T: S[t][q], t split in two 32-row Mtiles
    f32x16 s0, s1;
#pragma unroll
    for (int i = 0; i < 16; ++i) { s0[i] = 0.f; s1[i] = 0.f; }
    __builtin_amdgcn_s_setprio(1);
#pragma unroll
    for (int db = 0; db < 4; ++db) {
      const s16x8 k0 = *(const s16x8*)&kb2[row0 + c4[db]];
      const s16x8 k1 = *(const s16x8*)&kb2[row1 + c4[db]];
      s0 = MFMA32(k0, qf[db], s0);
      s1 = MFMA32(k1, qf[db], s1);
    }
    __builtin_amdgcn_s_setprio(0);
    // exp2 + l + pack (pairs are t-consecutive: regs (2i, 2i+1))
    unsigned pk0[8], pk1[8];
    float la = 0.f, lb = 0.f;
#pragma unroll
    for (int i = 0; i < 8; ++i) {
      float a0 = __builtin_amdgcn_exp2f(s0[2 * i]);
      float b0 = __builtin_amdgcn_exp2f(s0[2 * i + 1]);
      float a1 = __builtin_amdgcn_exp2f(s1[2 * i]);
      float b1 = __builtin_amdgcn_exp2f(s1[2 * i + 1]);
      la += bf16_floor(a0) + bf16_floor(b0);
      lb += bf16_floor(a1) + bf16_floor(b1);
      pk0[i] = pk_trunc(a0, b0);
      pk1[i] = pk_trunc(a1, b1);
    }
    l_lane += la + lb;
    // B-frags: slice0 t0..15 (pk0[0..3]), slice1 t16..31 (pk0[4..7]),
    //          slice2 t32..47 (pk1[0..3]), slice3 t48..63 (pk1[4..7])
    s16x8 pf0 = mkfrag(pk0[0], pk0[1], pk0[2], pk0[3]);
    s16x8 pf1 = mkfrag(pk0[4], pk0[5], pk0[6], pk0[7]);
    s16x8 pf2 = mkfrag(pk1[0], pk1[1], pk1[2], pk1[3]);
    s16x8 pf3 = mkfrag(pk1[4], pk1[5], pk1[6], pk1[7]);
    // PV: co[d][q] += V[d][t] * P[t][q]
    __builtin_amdgcn_s_setprio(1);
#pragma unroll
    for (int sl = 0; sl < 4; ++sl) {
      const s16x8 v0 = *(const s16x8*)&vb2[row0 + c4[sl]];
      const s16x8 v1 = *(const s16x8*)&vb2[row1 + c4[sl]];
      const s16x8 pf = (sl == 0) ? pf0 : (sl == 1) ? pf1 : (sl == 2) ? pf2 : pf3;
      co0 = MFMA32(v0, pf, co0);
      co1 = MFMA32(v1, pf, co1);
    }
    __builtin_amdgcn_s_setprio(0);
  };

  constexpr int NT = S_LEN / 64;   // 32 tiles, 16 phases
  fetch_pair(0, 64);
  store_pair();
  for (int ph = 0; ph < NT / 2; ++ph) {
    __syncthreads();                               // both buffers ready
    const long tE = (2 * ph + 2 < NT) ? (long)(2 * ph + 2) * 64 : 0;
    const long tO = (2 * ph + 3 < NT) ? (long)(2 * ph + 3) * 64 : 0;
    fetch_pair(tE, tO);                            // overlap with step
    step();                                        // wave's parity tile
    __syncthreads();                               // all done reading
    store_pair();                                  // refill both buffers
  }

  // l: combine the two t-half lanes (same q) of this wave's tiles
  float rs = l_lane + __shfl_xor(l_lane, 32);

  // ---- cross-parity merge via LDS (stride 36 floats = 144B, 16B-aligned) ----
  __syncthreads();
  float* mbuf = (float*)((rh == 0) ? (short*)kbuf : (short*)vbuf);
  float* mp = mbuf + lane * 36;
  if (par) {
#pragma unroll
    for (int i = 0; i < 4; ++i) {
      *(float4*)(mp + 4 * i)      = make_float4(co0[4*i], co0[4*i+1], co0[4*i+2], co0[4*i+3]);
      *(float4*)(mp + 16 + 4 * i) = make_float4(co1[4*i], co1[4*i+1], co1[4*i+2], co1[4*i+3]);
    }
    mp[32] = rs;
  }
  __syncthreads();
  if (!par) {
#pragma unroll
    for (int i = 0; i < 4; ++i) {
      float4 a = *(const float4*)(mp + 4 * i);
      float4 b = *(const float4*)(mp + 16 + 4 * i);
      co0[4*i] += a.x; co0[4*i+1] += a.y; co0[4*i+2] += a.z; co0[4*i+3] += a.w;
      co1[4*i] += b.x; co1[4*i+1] += b.y; co1[4*i+2] += b.z; co1[4*i+3] += b.w;
    }
    rs += mp[32];
    const float invl = 1.f / rs;

    const int hh = bh % NHEAD;
    const long tok = (long)(bh / NHEAD) * S_LEN + qs0 + rh * 32 + q32;
    short* outp = Ctx + tok * DMODEL + hh * 64;
    // reg r -> d = (r&3) + 8*(r>>2) + 4*hi (+32 for co1)
#pragma unroll
    for (int rq = 0; rq < 4; ++rq) {
      const int d0 = 8 * rq + 4 * hi;
      uint2 ov;
      ov.x = pk_bf16(co0[4*rq] * invl, co0[4*rq+1] * invl);
      ov.y = pk_bf16(co0[4*rq+2] * invl, co0[4*rq+3] * invl);
      *(uint2*)(outp + d0) = ov;
      uint2 ov2;
      ov2.x = pk_bf16(co1[4*rq] * invl, co1[4*rq+1] * invl);
      ov2.y = pk_bf16(co1[4*rq+2] * invl, co1[4*rq+3] * invl);
      *(uint2*)(outp + 32 + d0) = ov2;
    }
  }
}

// ---------------------------------------------------------------------------
extern "C" void kernel_launch(void* const* d_in, const int* in_sizes, int n_in,
                              void* d_out, int out_size, void* d_ws, size_t ws_size,
                              hipStream_t stream) {
  const float* q   = (const float*)d_in[0];
  const float* k   = (const float*)d_in[1];
  const float* v   = (const float*)d_in[2];
  const float* w_q = (const float*)d_in[3];
  const float* b_q = (const float*)d_in[4];
  const float* w_k = (const float*)d_in[5];
  const float* b_k = (const float*)d_in[6];
  const float* w_v = (const float*)d_in[7];
  const float* b_v = (const float*)d_in[8];
  const float* w_o = (const float*)d_in[9];
  const float* b_o = (const float*)d_in[10];
  float* out = (float*)d_out;

  const long NELEM = (long)2 * NHEAD * S_LEN * 64;  // 3,145,728
  const long WELEM = (long)DMODEL * DMODEL;         // 589,824
  short* qh  = (short*)d_ws;
  short* kh  = qh + NELEM;
  short* vt  = kh + NELEM;
  short* wqb = vt + NELEM;
  short* wkb = wqb + WELEM;
  short* wvb = wkb + WELEM;
  short* wob = wvb + WELEM;
  short* qb  = wob + WELEM;
  short* kb  = qb + NELEM;
  short* vb  = kb + NELEM;
  short* ctx = qb;   // alias: qb dead after qkv_kernel; attn writes ctx after

  dim3 blk(256);
  convert_all<<<dim3(11520), blk, 0, stream>>>(q, k, v, w_q, w_k, w_v, w_o,
                                               qb, kb, vb, wqb, wkb, wvb, wob);
  qkv_kernel<<<dim3(576), blk, 0, stream>>>(qb, kb, vb, wqb, wkb, wvb,
                                            b_q, b_k, b_v, qh, kh, vt);
  attn_kernel<<<dim3(32, 24), blk, 0, stream>>>(qh, kh, vt, ctx);
  o_kernel<<<dim3(384), blk, 0, stream>>>(ctx, wob, b_o, out);
}